// Round 1
// baseline (533.885 us; speedup 1.0000x reference)
//
#include <hip/hip_runtime.h>
#include <hip/hip_bf16.h>

// Problem constants: B=256, N=128, EB=5, NA=64, DIM=512, NIT=3
// out = [logit (256 f32), graph_repr (256*512 f32)]

typedef __bf16 bf16;
typedef __bf16 bf16x8 __attribute__((ext_vector_type(8)));
typedef float floatx4 __attribute__((ext_vector_type(4)));

// ---------------------------------------------------------------- convert node f32 -> bf16
__global__ __launch_bounds__(256) void k_cvt_node(const float* __restrict__ in,
                                                  bf16* __restrict__ out, int n) {
    int i = blockIdx.x * 256 + threadIdx.x;
    if (i < n) out[i] = (bf16)in[i];
}

// ---------------------------------------------------------------- Asum[b,n,m] = sum_e adj[b,n,m,1..4]
__global__ __launch_bounds__(256) void k_asum(const float* __restrict__ adj,
                                              bf16* __restrict__ asum, int total) {
    int i = blockIdx.x * 256 + threadIdx.x;
    if (i < total) {
        const float* p = adj + (size_t)i * 5;
        asum[i] = (bf16)(p[1] + p[2] + p[3] + p[4]);
    }
}

// ---------------------------------------------------------------- transpose [R,C] -> [C,R], out bf16
template <typename Tin>
__global__ __launch_bounds__(256) void k_transpose(const Tin* __restrict__ in, bf16* __restrict__ out,
                                                   int R, int C, long long sIn, long long sOut) {
    __shared__ bf16 tile[32][33];
    const Tin* src = in + (size_t)blockIdx.z * sIn;
    bf16* dst = out + (size_t)blockIdx.z * sOut;
    int c0 = blockIdx.x * 32, r0 = blockIdx.y * 32;
    int tx = threadIdx.x & 31, ty = threadIdx.x >> 5;  // 8 rows per pass, 4 passes
#pragma unroll
    for (int i = 0; i < 4; i++) {
        int r = ty + i * 8;
        tile[r][tx] = (bf16)(float)src[(size_t)(r0 + r) * C + c0 + tx];
    }
    __syncthreads();
#pragma unroll
    for (int i = 0; i < 4; i++) {
        int c = ty + i * 8;
        dst[(size_t)(c0 + c) * R + r0 + tx] = tile[tx][c];
    }
}

// ---------------------------------------------------------------- generic bf16 MFMA GEMM
// C[M,N] = op(A[M,K] @ BT[N,K]^T + bias + addend), all tiles exact multiples:
// M % 128 == 0, N % 128 == 0, K % 32 == 0.
#define BK 32
#define BKP 40  // padded LDS row stride (80B -> 2-way bank aliasing, free)

__global__ __launch_bounds__(256) void k_gemm(
    const bf16* __restrict__ A,    // [M,K] row-major
    const bf16* __restrict__ BT,   // [N,K] row-major (B transposed)
    const float* __restrict__ bias,   // [N] or nullptr
    const bf16* __restrict__ addend,  // [M,N] (same layout/batch-stride as C) or nullptr
    bf16* __restrict__ C,          // [M,N]
    int M, int N, int K,
    long long bsA, long long bsBT, long long bsC,
    int relu) {
    __shared__ __align__(16) bf16 As[128 * BKP];
    __shared__ __align__(16) bf16 Bs[128 * BKP];

    int bz = blockIdx.z;
    const bf16* Ab = A + bsA * bz + (size_t)blockIdx.y * 128 * K;
    const bf16* Bb = BT + bsBT * bz + (size_t)blockIdx.x * 128 * K;
    const bf16* addb = addend ? addend + bsC * bz + (size_t)blockIdx.y * 128 * N + blockIdx.x * 128 : nullptr;
    bf16* Cb = C + bsC * bz + (size_t)blockIdx.y * 128 * N + blockIdx.x * 128;

    int tid = threadIdx.x;
    int lane = tid & 63, w = tid >> 6;
    int wm = w >> 1, wn = w & 1;
    int q = lane >> 4, l16 = lane & 15;

    // staging slot decode: 512 uint4 slots per tile (128 rows x 4 chunks of 8 bf16)
    int s0 = tid, s1 = tid + 256;
    int r0 = s0 >> 2, kc0 = (s0 & 3) * 8;
    int r1 = s1 >> 2, kc1 = (s1 & 3) * 8;

    floatx4 acc[4][4] = {};

    for (int k0 = 0; k0 < K; k0 += BK) {
        uint4 av0 = *(const uint4*)(Ab + (size_t)r0 * K + k0 + kc0);
        uint4 av1 = *(const uint4*)(Ab + (size_t)r1 * K + k0 + kc1);
        uint4 bv0 = *(const uint4*)(Bb + (size_t)r0 * K + k0 + kc0);
        uint4 bv1 = *(const uint4*)(Bb + (size_t)r1 * K + k0 + kc1);
        *(uint4*)&As[r0 * BKP + kc0] = av0;
        *(uint4*)&As[r1 * BKP + kc1] = av1;
        *(uint4*)&Bs[r0 * BKP + kc0] = bv0;
        *(uint4*)&Bs[r1 * BKP + kc1] = bv1;
        __syncthreads();

        bf16x8 af[4], bfr[4];
#pragma unroll
        for (int mt = 0; mt < 4; mt++)
            af[mt] = *(const bf16x8*)&As[(wm * 64 + mt * 16 + l16) * BKP + q * 8];
#pragma unroll
        for (int nt = 0; nt < 4; nt++)
            bfr[nt] = *(const bf16x8*)&Bs[(wn * 64 + nt * 16 + l16) * BKP + q * 8];
#pragma unroll
        for (int mt = 0; mt < 4; mt++)
#pragma unroll
            for (int nt = 0; nt < 4; nt++)
                acc[mt][nt] = __builtin_amdgcn_mfma_f32_16x16x32_bf16(af[mt], bfr[nt], acc[mt][nt], 0, 0, 0);
        __syncthreads();
    }

    // epilogue: C/D layout col = lane&15, row = quad*4 + reg
#pragma unroll
    for (int mt = 0; mt < 4; mt++) {
#pragma unroll
        for (int nt = 0; nt < 4; nt++) {
            int col = wn * 64 + nt * 16 + l16;
            float bv = bias ? bias[blockIdx.x * 128 + col] : 0.f;
#pragma unroll
            for (int r = 0; r < 4; r++) {
                int row = wm * 64 + mt * 16 + q * 4 + r;
                float v = acc[mt][nt][r] + bv;
                if (addb) v += (float)addb[(size_t)row * N + col];
                if (relu) v = fmaxf(v, 0.f);
                Cb[(size_t)row * N + col] = (bf16)v;
            }
        }
    }
}

// ---------------------------------------------------------------- mean over N + logit
__global__ __launch_bounds__(256) void k_finalize(const bf16* __restrict__ h,
                                                  const float* __restrict__ W_out,
                                                  const float* __restrict__ b_out,
                                                  float* __restrict__ out) {
    int b = blockIdx.x, t = threadIdx.x;
    const bf16* hb = h + (size_t)b * 128 * 512;
    float a0 = 0.f, a1 = 0.f;
    for (int n = 0; n < 128; n++) {
        a0 += (float)hb[n * 512 + t];
        a1 += (float)hb[n * 512 + 256 + t];
    }
    float g0 = a0 * (1.f / 128.f), g1 = a1 * (1.f / 128.f);
    out[256 + (size_t)b * 512 + t] = g0;
    out[256 + (size_t)b * 512 + 256 + t] = g1;
    __shared__ float red[256];
    red[t] = g0 * W_out[t] + g1 * W_out[256 + t];
    __syncthreads();
    for (int s = 128; s > 0; s >>= 1) {
        if (t < s) red[t] += red[t + s];
        __syncthreads();
    }
    if (t == 0) out[b] = red[0] + b_out[0];
}

// ---------------------------------------------------------------- launch
extern "C" void kernel_launch(void* const* d_in, const int* in_sizes, int n_in,
                              void* d_out, int out_size, void* d_ws, size_t ws_size,
                              hipStream_t stream) {
    const float* adj      = (const float*)d_in[0];
    // d_in[1] = hidden (unused by forward)
    const float* node     = (const float*)d_in[2];
    const float* W_embed  = (const float*)d_in[3];
    const float* b_embed  = (const float*)d_in[4];
    const float* W_layers = (const float*)d_in[5];
    const float* b_layers = (const float*)d_in[6];
    const float* W_out    = (const float*)d_in[7];
    const float* b_out    = (const float*)d_in[8];
    float* out = (float*)d_out;

    char* ws = (char*)d_ws;
    bf16* nodeb = (bf16*)(ws);              //  4,194,304 B : node bf16 [32768,64]
    bf16* Web_t = (bf16*)(ws + 4194304);    //     65,536 B : W_embed^T bf16 [512,64]
    bf16* Wlb_t = (bf16*)(ws + 4259840);    //  1,572,864 B : W_layers^T bf16 [3][512,512]
    bf16* Asum  = (bf16*)(ws + 5832704);    //  8,388,608 B : [256][128,128]
    bf16* h     = (bf16*)(ws + 14221312);   // 33,554,432 B : [256][128,512]
    bf16* t     = (bf16*)(ws + 47775744);   // 33,554,432 B : [256][128,512]
    bf16* h_t   = (bf16*)(ws + 81330176);   // 33,554,432 B : [256][512,128]  (end 114.9 MB)

    k_cvt_node<<<8192, 256, 0, stream>>>(node, nodeb, 2097152);
    k_transpose<float><<<dim3(16, 2, 1), 256, 0, stream>>>(W_embed, Web_t, 64, 512, 0, 0);
    k_transpose<float><<<dim3(16, 16, 3), 256, 0, stream>>>(W_layers, Wlb_t, 512, 512, 262144, 262144);
    k_asum<<<16384, 256, 0, stream>>>(adj, Asum, 4194304);

    // h = node @ W_embed + b_embed
    k_gemm<<<dim3(4, 256, 1), 256, 0, stream>>>(nodeb, Web_t, b_embed, nullptr, h,
                                                32768, 512, 64, 0, 0, 0, 0);
    for (int i = 0; i < 3; i++) {
        // h_t[b] = h[b]^T  (for B-operand staging)
        k_transpose<bf16><<<dim3(16, 4, 256), 256, 0, stream>>>(h, h_t, 128, 512, 65536, 65536);
        // t[b] = h[b] + Asum[b] @ h[b]
        k_gemm<<<dim3(4, 1, 256), 256, 0, stream>>>(Asum, h_t, nullptr, h, t,
                                                    128, 512, 128, 16384, 65536, 65536, 0);
        // h = relu(t @ W_i + b_i)
        k_gemm<<<dim3(4, 256, 1), 256, 0, stream>>>(t, Wlb_t + (size_t)i * 262144, b_layers + i * 512,
                                                    nullptr, h, 32768, 512, 512, 0, 0, 0, 1);
    }
    k_finalize<<<256, 256, 0, stream>>>(h, W_out, b_out, out);
}

// Round 2
// 412.370 us; speedup vs baseline: 1.2947x; 1.2947x over previous
//
#include <hip/hip_runtime.h>
#include <hip/hip_bf16.h>

// Problem constants: B=256, N=128, EB=5, NA=64, DIM=512, NIT=3
// out = [logit (256 f32), graph_repr (256*512 f32)]

typedef __bf16 bf16;
typedef __bf16 bf16x4 __attribute__((ext_vector_type(4)));
typedef __bf16 bf16x8 __attribute__((ext_vector_type(8)));
typedef float floatx4 __attribute__((ext_vector_type(4)));

__device__ __forceinline__ void glds16(const void* g, void* l) {
    __builtin_amdgcn_global_load_lds((const __attribute__((address_space(1))) unsigned int*)g,
                                     (__attribute__((address_space(3))) unsigned int*)l,
                                     16, 0, 0);
}

// ---------------------------------------------------------------- convert node f32 -> bf16, 8/thread
__global__ __launch_bounds__(256) void k_cvt_node(const float* __restrict__ in,
                                                  bf16* __restrict__ out) {
    int i = (blockIdx.x * 256 + threadIdx.x) * 8;
    float4 a = *(const float4*)(in + i);
    float4 b = *(const float4*)(in + i + 4);
    bf16x8 v;
    v[0] = (bf16)a.x; v[1] = (bf16)a.y; v[2] = (bf16)a.z; v[3] = (bf16)a.w;
    v[4] = (bf16)b.x; v[5] = (bf16)b.y; v[6] = (bf16)b.z; v[7] = (bf16)b.w;
    *(bf16x8*)(out + i) = v;
}

// ---------------------------------------------------------------- Ahat[b,n,m] = sum_e adj[...,1:] + (n==m)
// 4 elements (20 floats = 5 float4) per thread.
__global__ __launch_bounds__(256) void k_asum(const float* __restrict__ adj,
                                              bf16* __restrict__ ahat) {
    int i = blockIdx.x * 256 + threadIdx.x;   // group of 4 elements
    int base = i * 4;
    const float4* p = (const float4*)(adj + (size_t)base * 5);
    float4 v0 = p[0], v1 = p[1], v2 = p[2], v3 = p[3], v4 = p[4];
    float s[4];
    s[0] = v0.y + v0.z + v0.w + v1.x;
    s[1] = v1.z + v1.w + v2.x + v2.y;
    s[2] = v2.w + v3.x + v3.y + v3.z;
    s[3] = v4.x + v4.y + v4.z + v4.w;
    bf16x4 o;
#pragma unroll
    for (int j = 0; j < 4; j++) {
        int e = base + j;
        int m = e & 127, n = (e >> 7) & 127;
        float v = s[j] + ((n == m) ? 1.0f : 0.0f);
        o[j] = (bf16)v;
    }
    *(bf16x4*)(ahat + base) = o;
}

// ---------------------------------------------------------------- transpose [R,C] -> [C,R], out bf16 (weights only)
template <typename Tin>
__global__ __launch_bounds__(256) void k_transpose(const Tin* __restrict__ in, bf16* __restrict__ out,
                                                   int R, int C, long long sIn, long long sOut) {
    __shared__ bf16 tile[32][33];
    const Tin* src = in + (size_t)blockIdx.z * sIn;
    bf16* dst = out + (size_t)blockIdx.z * sOut;
    int c0 = blockIdx.x * 32, r0 = blockIdx.y * 32;
    int tx = threadIdx.x & 31, ty = threadIdx.x >> 5;
#pragma unroll
    for (int i = 0; i < 4; i++) {
        int r = ty + i * 8;
        tile[r][tx] = (bf16)(float)src[(size_t)(r0 + r) * C + c0 + tx];
    }
    __syncthreads();
#pragma unroll
    for (int i = 0; i < 4; i++) {
        int c = ty + i * 8;
        dst[(size_t)(c0 + c) * R + r0 + tx] = tile[tx][c];
    }
}

// ---------------------------------------------------------------- bf16 MFMA GEMM, m97-style staging
// C[M,N] = act(A[M,K] @ BT[N,K]^T + bias). Optionally writes C (normal) and/or
// Ct (per-128-row-tile transposed: Ct[rt][N][128], N must be 512 when Ct != null).
// M%128==0, N%128==0, K%32==0.
#define BK 32

__global__ __launch_bounds__(256) void k_gemm(
    const bf16* __restrict__ A,    // [M,K] row-major
    const bf16* __restrict__ BT,   // [N,K] row-major
    const float* __restrict__ bias,   // [N] or nullptr
    bf16* __restrict__ C,          // [M,N] or nullptr
    bf16* __restrict__ Ct,         // [M/128][N][128] or nullptr
    int M, int N, int K,
    long long bsA, long long bsBT, long long bsC,
    int relu) {
    __shared__ __align__(16) bf16 As[128 * BK];
    __shared__ __align__(16) bf16 Bs[128 * BK];

    int bz = blockIdx.z;
    const bf16* Ab = A + bsA * bz + (size_t)blockIdx.y * 128 * K;
    const bf16* Bb = BT + bsBT * bz + (size_t)blockIdx.x * 128 * K;

    int tid = threadIdx.x;
    int lane = tid & 63, w = tid >> 6;
    int wm = w >> 1, wn = w & 1;
    int q = lane >> 4, l16 = lane & 15;

    floatx4 acc[4][4] = {};

    for (int k0 = 0; k0 < K; k0 += BK) {
        // stage: 512 chunks of 16B per operand; swizzled physical chunk = logical ^ (row&3)
#pragma unroll
        for (int s = 0; s < 2; s++) {
            int p = s * 256 + w * 64 + lane;
            int r = p >> 2, c = p & 3;
            int kc = c ^ (r & 3);
            char* la = (char*)As + (size_t)(s * 256 + w * 64) * 16;
            char* lb = (char*)Bs + (size_t)(s * 256 + w * 64) * 16;
            glds16(Ab + (size_t)r * K + k0 + kc * 8, la);
            glds16(Bb + (size_t)r * K + k0 + kc * 8, lb);
        }
        __syncthreads();

        bf16x8 af[4], bfr[4];
#pragma unroll
        for (int mt = 0; mt < 4; mt++) {
            int row = wm * 64 + mt * 16 + l16;
            af[mt] = *(const bf16x8*)&As[row * BK + ((q ^ (row & 3)) * 8)];
        }
#pragma unroll
        for (int nt = 0; nt < 4; nt++) {
            int row = wn * 64 + nt * 16 + l16;
            bfr[nt] = *(const bf16x8*)&Bs[row * BK + ((q ^ (row & 3)) * 8)];
        }
#pragma unroll
        for (int mt = 0; mt < 4; mt++)
#pragma unroll
            for (int nt = 0; nt < 4; nt++)
                acc[mt][nt] = __builtin_amdgcn_mfma_f32_16x16x32_bf16(af[mt], bfr[nt], acc[mt][nt], 0, 0, 0);
        __syncthreads();
    }

    // epilogue: C/D layout col = lane&15, row = quad*4 + reg
    int rt = blockIdx.y + bz * gridDim.y;  // 128-row tile index (one of y/z is 0)
    bf16* Cb = C ? C + bsC * bz + (size_t)blockIdx.y * 128 * N + blockIdx.x * 128 : nullptr;
    bf16* Ctb = Ct ? Ct + (size_t)rt * N * 128 + (size_t)blockIdx.x * 128 * 128 : nullptr;

#pragma unroll
    for (int mt = 0; mt < 4; mt++) {
#pragma unroll
        for (int nt = 0; nt < 4; nt++) {
            int col = wn * 64 + nt * 16 + l16;
            float bv = bias ? bias[blockIdx.x * 128 + col] : 0.f;
            int row0 = wm * 64 + mt * 16 + q * 4;
            float v[4];
#pragma unroll
            for (int r = 0; r < 4; r++) {
                v[r] = acc[mt][nt][r] + bv;
                if (relu) v[r] = fmaxf(v[r], 0.f);
            }
            if (Cb) {
#pragma unroll
                for (int r = 0; r < 4; r++)
                    Cb[(size_t)(row0 + r) * N + col] = (bf16)v[r];
            }
            if (Ctb) {
                bf16x4 pk;
#pragma unroll
                for (int r = 0; r < 4; r++) pk[r] = (bf16)v[r];
                *(bf16x4*)&Ctb[(size_t)col * 128 + row0] = pk;
            }
        }
    }
}

// ---------------------------------------------------------------- mean over nodes + logit, from h_t [B][512][128]
__global__ __launch_bounds__(256) void k_finalize(const bf16* __restrict__ ht,
                                                  const float* __restrict__ W_out,
                                                  const float* __restrict__ b_out,
                                                  float* __restrict__ out) {
    int b = blockIdx.x, t = threadIdx.x;
    const bf16* hb = ht + (size_t)b * 65536;
    float partial = 0.f;
#pragma unroll
    for (int j = 0; j < 2; j++) {
        int d = t + j * 256;
        const bf16* p = hb + (size_t)d * 128;
        float s = 0.f;
        for (int i = 0; i < 128; i += 8) {
            bf16x8 v = *(const bf16x8*)&p[i];
#pragma unroll
            for (int k = 0; k < 8; k++) s += (float)v[k];
        }
        float g = s * (1.f / 128.f);
        out[256 + (size_t)b * 512 + d] = g;
        partial += g * W_out[d];
    }
    __shared__ float red[256];
    red[t] = partial;
    __syncthreads();
    for (int s = 128; s > 0; s >>= 1) {
        if (t < s) red[t] += red[t + s];
        __syncthreads();
    }
    if (t == 0) out[b] = red[0] + b_out[0];
}

// ---------------------------------------------------------------- launch
extern "C" void kernel_launch(void* const* d_in, const int* in_sizes, int n_in,
                              void* d_out, int out_size, void* d_ws, size_t ws_size,
                              hipStream_t stream) {
    const float* adj      = (const float*)d_in[0];
    // d_in[1] = hidden (unused by forward)
    const float* node     = (const float*)d_in[2];
    const float* W_embed  = (const float*)d_in[3];
    const float* b_embed  = (const float*)d_in[4];
    const float* W_layers = (const float*)d_in[5];
    const float* b_layers = (const float*)d_in[6];
    const float* W_out    = (const float*)d_in[7];
    const float* b_out    = (const float*)d_in[8];
    float* out = (float*)d_out;

    char* ws = (char*)d_ws;
    bf16* nodeb = (bf16*)(ws);              //  4,194,304 B : node bf16 [32768,64]
    bf16* Web_t = (bf16*)(ws + 4194304);    //     65,536 B : W_embed^T bf16 [512,64]
    bf16* Wlb_t = (bf16*)(ws + 4259840);    //  1,572,864 B : W_layers^T bf16 [3][512,512]
    bf16* Ahat  = (bf16*)(ws + 5832704);    //  8,388,608 B : (Asum + I) [256][128,128]
    bf16* h_t   = (bf16*)(ws + 14221312);   // 33,554,432 B : h transposed [256][512,128]
    bf16* t     = (bf16*)(ws + 47775744);   // 33,554,432 B : t normal [256][128,512] (end 81.3 MB)

    k_cvt_node<<<1024, 256, 0, stream>>>(node, nodeb);
    k_transpose<float><<<dim3(16, 2, 1), 256, 0, stream>>>(W_embed, Web_t, 64, 512, 0, 0);
    k_transpose<float><<<dim3(16, 16, 3), 256, 0, stream>>>(W_layers, Wlb_t, 512, 512, 262144, 262144);
    k_asum<<<4096, 256, 0, stream>>>(adj, Ahat);

    // h_t = (node @ W_embed + b_embed)^T per batch
    k_gemm<<<dim3(4, 256, 1), 256, 0, stream>>>(nodeb, Web_t, b_embed, nullptr, h_t,
                                                32768, 512, 64, 0, 0, 0, 0);
    for (int i = 0; i < 3; i++) {
        // t[b] = Ahat[b] @ h[b]   (== h + sum_e A_e @ h)
        k_gemm<<<dim3(4, 1, 256), 256, 0, stream>>>(Ahat, h_t, nullptr, t, nullptr,
                                                    128, 512, 128, 16384, 65536, 65536, 0);
        // h_t = relu(t @ W_i + b_i)^T per batch
        k_gemm<<<dim3(4, 256, 1), 256, 0, stream>>>(t, Wlb_t + (size_t)i * 262144, b_layers + i * 512,
                                                    nullptr, h_t, 32768, 512, 512, 0, 0, 0, 1);
    }
    k_finalize<<<256, 256, 0, stream>>>(h_t, W_out, b_out, out);
}